// Round 4
// baseline (971.720 us; speedup 1.0000x reference)
//
#include <hip/hip_runtime.h>
#include <math.h>

// pLayer forward + power, MI355X fp32.
// V=8 noise draws, E=32768 batch, M=130 (=128 inputs + const-1 + const-0), N=128.
//
// Decomposition:
//   z[v,e,n] = sum_{m<128} x*Wp + xn*Wn  + bias[v,n]
//   u[v,e,n] = sum_{m<128} x*Dp + xn*Dn          (Dp=g*p, Dn=g*(1-p))
//   power*E*V = sum_v [ sum_m rowDp*Sx2 + rowDn*Sxn2 - 2*(sum z*u + sum_n c128*Sz)
//                       + sum_n gsum*Sy2 ] + E*sum_{v,n}(d128p + inv1^2*d128n)
// so the whole power reduces to one scalar per block (deterministic slot write).

#define V_N 8
#define E_N 32768
#define M_N 130
#define N_N 128
#define BE  64
#define LDP 132   // LDS row stride in floats: 16B-aligned, 2-way bank aliasing (free)

__device__ __forceinline__ float inv_f(float a) {
    // ETA_INV = (-0.05, -0.95, 0.0, 2.0)
    return -0.05f - 0.95f * tanhf(2.0f * a);
}
__device__ __forceinline__ float act_f(float z) {
    // ETA = (0.01, 0.5, 0.05, 10.0)
    return 0.01f + 0.5f * tanhf((z - 0.05f) * 10.0f);
}
__device__ __forceinline__ float thr_f(float th) {
    float tc = fminf(fmaxf(th, -1.0f), 1.0f);   // clip(+-GMAX)
    return (fabsf(tc) < 0.01f) ? 0.0f : tc;     // threshold at GMIN
}

// ---------- prep0: per-column min of |theta_| -> colscale, and gsum ----------
__global__ void prep0_kernel(const float* __restrict__ theta,
                             float* __restrict__ colscale,
                             float* __restrict__ gsum) {
    int n = threadIdx.x;  // 128 threads
    float mn = 3.4e38f;
    for (int m = 0; m < M_N; ++m) mn = fminf(mn, fabsf(theta[m * N_N + n]));
    float sc = 0.01f / mn;          // PGMIN / colmin
    float gs = 0.f;
    for (int m = 0; m < M_N; ++m) gs += fabsf(theta[m * N_N + n]) * sc;
    colscale[n] = sc;
    gsum[n] = gs;
}

// ---------- prep1: build Wp,Wn,Dp,Dn (m<128) + bias,c128,d128p,d128n ----------
__global__ void prep1_kernel(const float* __restrict__ theta,
                             const float* __restrict__ nw,
                             const float* __restrict__ npos,
                             const float* __restrict__ npow,
                             const float* __restrict__ colscale,
                             float* __restrict__ Wp, float* __restrict__ Wn,
                             float* __restrict__ Dp, float* __restrict__ Dn,
                             float* __restrict__ bias, float* __restrict__ c128,
                             float* __restrict__ d128p, float* __restrict__ d128n) {
    int v = blockIdx.x;    // 8 blocks
    int n = threadIdx.x;   // 128 threads, coalesced along n
    const float inv1 = inv_f(1.0f);

    float G = 0.f;
    for (int m = 0; m < M_N; ++m) {
        float tt = thr_f(theta[m * N_N + n]);
        G += fabsf(tt * nw[(v * M_N + m) * N_N + n]);
    }
    float Gd = G + 1e-10f;
    float sc = colscale[n];

    for (int m = 0; m < M_N; ++m) {
        float th = theta[m * N_N + n];
        float tt = thr_f(th);
        int ni = (v * M_N + m) * N_N + n;
        float w   = fabsf(tt * nw[ni]) / Gd;
        float pos = (tt * npos[ni] >= 0.f) ? 1.f : 0.f;
        float wp = pos * w, wn = w - wp;
        float g  = fabsf(th) * sc;
        float pm = (tt * npow[ni] >= 0.f) ? 1.f : 0.f;
        float dp = pm * g, dn = g - dp;
        if (m < 128) {
            int oi = (v * 128 + m) * 128 + n;
            Wp[oi] = wp; Wn[oi] = wn; Dp[oi] = dp; Dn[oi] = dn;
        } else if (m == 128) {
            bias[v * 128 + n]  = wp + inv1 * wn;   // x=1, xn=inv(1)
            c128[v * 128 + n]  = dp + inv1 * dn;   // coefficient of Sz
            d128p[v * 128 + n] = dp;
            d128n[v * 128 + n] = dn;
        }
        // m==129: x=0 and xn=0 -> no z/power contribution (g still in gsum)
    }
}

// ---------- prep2: row sums of Dp/Dn over n ----------
__global__ void prep2_kernel(const float* __restrict__ Dp, const float* __restrict__ Dn,
                             float* __restrict__ rowDp, float* __restrict__ rowDn) {
    int t = threadIdx.x;   // 1024 threads = (v,m<128)
    const float* dp = Dp + (size_t)t * 128;
    const float* dn = Dn + (size_t)t * 128;
    float sp = 0.f, sn = 0.f;
    for (int n4 = 0; n4 < 32; ++n4) {
        float4 a = *(const float4*)(dp + n4 * 4);
        float4 b = *(const float4*)(dn + n4 * 4);
        sp += a.x + a.y + a.z + a.w;
        sn += b.x + b.y + b.z + b.w;
    }
    rowDp[t] = sp; rowDn[t] = sn;
}

// ---------- main: fused dual GEMM + activation + power partials ----------
__global__ __launch_bounds__(256, 2)
void pmain_kernel(const float* __restrict__ a,
                  const float* __restrict__ Wp, const float* __restrict__ Wn,
                  const float* __restrict__ Dp, const float* __restrict__ Dn,
                  const float* __restrict__ bias, const float* __restrict__ c128,
                  const float* __restrict__ gsum,
                  const float* __restrict__ rowDp, const float* __restrict__ rowDn,
                  float* __restrict__ out, double* __restrict__ blockP) {
    __shared__ float xs[BE * LDP];
    __shared__ float xns[BE * LDP];

    const int tid = threadIdx.x;
    const int v  = blockIdx.y;
    const int e0 = blockIdx.x * BE;
    const float* aP   = a + ((size_t)v * E_N + e0) * N_N;

    // ---- load x tile, compute xn = inv(x); fold Sx2*rowDp and Sxn2*rowDn now ----
    // c4 = (p*256+tid)&31 == tid&31 for all p: hoist the rowDp/rowDn loads.
    const int c4 = tid & 31;
    float4 rp = *(const float4*)(rowDp + v * 128 + c4 * 4);
    float4 rn = *(const float4*)(rowDn + v * 128 + c4 * 4);
    float sxx = 0.f;
    #pragma unroll
    for (int p = 0; p < 8; ++p) {
        int row = p * 8 + (tid >> 5);   // e-row within tile
        float4 xv = *(const float4*)(aP + row * 128 + c4 * 4);
        float4 xnv;
        xnv.x = inv_f(xv.x); xnv.y = inv_f(xv.y);
        xnv.z = inv_f(xv.z); xnv.w = inv_f(xv.w);
        sxx += xv.x * xv.x * rp.x + xv.y * xv.y * rp.y
             + xv.z * xv.z * rp.z + xv.w * xv.w * rp.w;
        sxx += xnv.x * xnv.x * rn.x + xnv.y * xnv.y * rn.y
             + xnv.z * xnv.z * rn.z + xnv.w * xnv.w * rn.w;
        *(float4*)(xs  + row * LDP + c4 * 4) = xv;
        *(float4*)(xns + row * LDP + c4 * 4) = xnv;
    }
    __syncthreads();

    // ---- dual register-tile GEMM: 4 e-rows x 8 n-cols per thread ----
    const int tx = tid & 15, ty = tid >> 4;
    const float* wpP = Wp + (size_t)v * 16384 + tx * 8;
    const float* wnP = Wn + (size_t)v * 16384 + tx * 8;
    const float* dpP = Dp + (size_t)v * 16384 + tx * 8;
    const float* dnP = Dn + (size_t)v * 16384 + tx * 8;
    const float* xbase  = xs  + (ty * 4) * LDP;
    const float* xnbase = xns + (ty * 4) * LDP;

    float accz[4][8], accu[4][8];
    #pragma unroll
    for (int i = 0; i < 4; ++i)
        #pragma unroll
        for (int j = 0; j < 8; ++j) { accz[i][j] = 0.f; accu[i][j] = 0.f; }

    for (int k0 = 0; k0 < 128; k0 += 4) {
        float xk[4][4], xnk[4][4];
        #pragma unroll
        for (int i = 0; i < 4; ++i) {
            float4 t1 = *(const float4*)(xbase  + i * LDP + k0);
            float4 t2 = *(const float4*)(xnbase + i * LDP + k0);
            xk[i][0] = t1.x; xk[i][1] = t1.y; xk[i][2] = t1.z; xk[i][3] = t1.w;
            xnk[i][0] = t2.x; xnk[i][1] = t2.y; xnk[i][2] = t2.z; xnk[i][3] = t2.w;
        }
        #pragma unroll
        for (int kk = 0; kk < 4; ++kk) {
            const int k = k0 + kk;
            float4 wpa = *(const float4*)(wpP + k * 128);
            float4 wpb = *(const float4*)(wpP + k * 128 + 4);
            float4 wna = *(const float4*)(wnP + k * 128);
            float4 wnb = *(const float4*)(wnP + k * 128 + 4);
            float4 dpa = *(const float4*)(dpP + k * 128);
            float4 dpb = *(const float4*)(dpP + k * 128 + 4);
            float4 dna = *(const float4*)(dnP + k * 128);
            float4 dnb = *(const float4*)(dnP + k * 128 + 4);
            float wpv[8] = {wpa.x, wpa.y, wpa.z, wpa.w, wpb.x, wpb.y, wpb.z, wpb.w};
            float wnv[8] = {wna.x, wna.y, wna.z, wna.w, wnb.x, wnb.y, wnb.z, wnb.w};
            float dpv[8] = {dpa.x, dpa.y, dpa.z, dpa.w, dpb.x, dpb.y, dpb.z, dpb.w};
            float dnv[8] = {dna.x, dna.y, dna.z, dna.w, dnb.x, dnb.y, dnb.z, dnb.w};
            #pragma unroll
            for (int i = 0; i < 4; ++i) {
                float xi = xk[i][kk], xni = xnk[i][kk];
                #pragma unroll
                for (int j = 0; j < 8; ++j) {
                    accz[i][j] = fmaf(xi, wpv[j], fmaf(xni, wnv[j], accz[i][j]));
                    accu[i][j] = fmaf(xi, dpv[j], fmaf(xni, dnv[j], accu[i][j]));
                }
            }
        }
    }

    // ---- epilogue: bias, activation, output store, power partials ----
    const float* bP = bias + v * 128 + tx * 8;
    const float* gP = gsum + tx * 8;
    const float* cP = c128 + v * 128 + tx * 8;
    float4 b0 = *(const float4*)bP,       b1 = *(const float4*)(bP + 4);
    float4 g0 = *(const float4*)gP,       g1 = *(const float4*)(gP + 4);
    float4 c0 = *(const float4*)cP,       c1 = *(const float4*)(cP + 4);
    float bv[8] = {b0.x, b0.y, b0.z, b0.w, b1.x, b1.y, b1.z, b1.w};
    float gv[8] = {g0.x, g0.y, g0.z, g0.w, g1.x, g1.y, g1.z, g1.w};
    float cv[8] = {c0.x, c0.y, c0.z, c0.w, c1.x, c1.y, c1.z, c1.w};

    float szu = 0.f, ssz = 0.f, sy2 = 0.f;
    size_t obase = ((size_t)v * E_N + e0 + ty * 4) * N_N + tx * 8;
    #pragma unroll
    for (int i = 0; i < 4; ++i) {
        float o[8];
        #pragma unroll
        for (int j = 0; j < 8; ++j) {
            float z = accz[i][j] + bv[j];
            szu += z * accu[i][j];
            sy2 += z * z * gv[j];
            ssz += z * cv[j];
            o[j] = act_f(z);
        }
        *(float4*)(out + obase + (size_t)i * N_N)     = make_float4(o[0], o[1], o[2], o[3]);
        *(float4*)(out + obase + (size_t)i * N_N + 4) = make_float4(o[4], o[5], o[6], o[7]);
    }

    float P = sxx - 2.0f * (szu + ssz) + sy2;
    #pragma unroll
    for (int off = 32; off > 0; off >>= 1) P += __shfl_down(P, off, 64);
    __syncthreads();                    // all xs reads done before reuse
    if ((tid & 63) == 0) xs[tid >> 6] = P;
    __syncthreads();
    if (tid == 0) {
        double tot = (double)xs[0] + (double)xs[1] + (double)xs[2] + (double)xs[3];
        blockP[blockIdx.y * gridDim.x + blockIdx.x] = tot;
    }
}

// ---------- finalize: sum block partials + constant columns, divide ----------
__global__ void pfinal_kernel(const double* __restrict__ blockP,
                              const float* __restrict__ d128p,
                              const float* __restrict__ d128n,
                              float* __restrict__ outP) {
    __shared__ double sd[256];
    int t = threadIdx.x;
    double s = 0.0;
    for (int i = t; i < 4096; i += 256) s += blockP[i];
    float inv1 = inv_f(1.0f);
    double i1sq = (double)inv1 * (double)inv1;
    double cc = 0.0;
    for (int i = t; i < V_N * 128; i += 256)
        cc += (double)d128p[i] + i1sq * (double)d128n[i];
    s += cc * (double)E_N;      // Sx2[v,128]=E, Sxn2[v,128]=E*inv1^2
    sd[t] = s;
    __syncthreads();
    for (int off = 128; off > 0; off >>= 1) {
        if (t < off) sd[t] += sd[t + off];
        __syncthreads();
    }
    if (t == 0) outP[0] = (float)(sd[0] / ((double)E_N * (double)V_N));
}

extern "C" void kernel_launch(void* const* d_in, const int* in_sizes, int n_in,
                              void* d_out, int out_size, void* d_ws, size_t ws_size,
                              hipStream_t stream) {
    const float* a     = (const float*)d_in[0];
    const float* theta = (const float*)d_in[1];
    const float* nw    = (const float*)d_in[2];
    const float* npos  = (const float*)d_in[3];
    const float* npow  = (const float*)d_in[4];
    float* out = (float*)d_out;

    // workspace layout: doubles first (alignment), then float arrays (~2.2 MB)
    double* blockP = (double*)d_ws;                       // 4096 doubles
    float* fb = (float*)((char*)d_ws + 4096 * sizeof(double));
    float* Wp = fb;                   // 8*128*128
    float* Wn = Wp + 131072;
    float* Dp = Wn + 131072;
    float* Dn = Dp + 131072;
    float* biasA = Dn + 131072;       // 1024 each below
    float* c128A = biasA + 1024;
    float* gsumA = c128A + 1024;      // 128
    float* colsc = gsumA + 128;       // 128
    float* d128p = colsc + 128;       // 1024
    float* d128n = d128p + 1024;      // 1024
    float* rowDpA = d128n + 1024;     // 1024
    float* rowDnA = rowDpA + 1024;    // 1024

    prep0_kernel<<<1, 128, 0, stream>>>(theta, colsc, gsumA);
    prep1_kernel<<<8, 128, 0, stream>>>(theta, nw, npos, npow, colsc,
                                        Wp, Wn, Dp, Dn, biasA, c128A, d128p, d128n);
    prep2_kernel<<<1, 1024, 0, stream>>>(Dp, Dn, rowDpA, rowDnA);
    dim3 grid(E_N / BE, V_N);
    pmain_kernel<<<grid, 256, 0, stream>>>(a, Wp, Wn, Dp, Dn, biasA, c128A, gsumA,
                                           rowDpA, rowDnA, out, blockP);
    pfinal_kernel<<<1, 256, 0, stream>>>(blockP, d128p, d128n,
                                         out + (size_t)V_N * E_N * N_N);
}

// Round 8
// 489.351 us; speedup vs baseline: 1.9857x; 1.9857x over previous
//
#include <hip/hip_runtime.h>
#include <math.h>

// pLayer forward + power, MI355X. MFMA bf16 hi/lo 3-pass split GEMM.
// z[v,e,n] = sum_{k<256} A[e,k]*Bz[k,n] + bias ; A = [x | xn], Bz = [Wp;Wn]
// u[v,e,n] = A·Bu, Bu = [Dp;Dn]
// power*E*V = sxx - 2*(sum z*u + c128·Sz) + gsum·Sy2 + E*(d128p + inv1^2*d128n)
// bf16x3 split: A*B ~= Ah*Bh + Ah*Bl + Al*Bh (error ~2^-18 rel, fp32-equivalent)

#define V_N 8
#define E_N 32768
#define M_N 130
#define N_N 128
#define BE  64
#define LDA 264   // A-tile row stride in bf16 units (33 granules -> conflict-free)
#define LDF 132   // epilogue f32 transpose stride

typedef float f32x4 __attribute__((ext_vector_type(4)));
typedef short s16x8 __attribute__((ext_vector_type(8)));

__device__ __forceinline__ float inv_f(float a) {
    return -0.05f - 0.95f * tanhf(2.0f * a);      // ETA_INV
}
__device__ __forceinline__ float act_f(float z) {
    return 0.01f + 0.5f * tanhf((z - 0.05f) * 10.0f);   // ETA
}
__device__ __forceinline__ float thr_f(float th) {
    float tc = fminf(fmaxf(th, -1.0f), 1.0f);
    return (fabsf(tc) < 0.01f) ? 0.0f : tc;
}
__device__ __forceinline__ ushort bf16_rne(float f) {
    unsigned u = __float_as_uint(f);
    return (ushort)((u + 0x7fffu + ((u >> 16) & 1u)) >> 16);
}
__device__ __forceinline__ void split2(float f, ushort& h, ushort& l) {
    ushort hh = bf16_rne(f);
    float fh = __uint_as_float(((unsigned)hh) << 16);
    h = hh;
    l = bf16_rne(f - fh);
}

// ---------- prep0: per-column min of |theta_| -> colscale, and gsum ----------
__global__ void prep0_kernel(const float* __restrict__ theta,
                             float* __restrict__ colscale,
                             float* __restrict__ gsum) {
    int n = threadIdx.x;  // 128 threads
    float mn = 3.4e38f;
    for (int m = 0; m < M_N; ++m) mn = fminf(mn, fabsf(theta[m * N_N + n]));
    float sc = 0.01f / mn;
    float gs = 0.f;
    for (int m = 0; m < M_N; ++m) gs += fabsf(theta[m * N_N + n]) * sc;
    colscale[n] = sc;
    gsum[n] = gs;
}

// ---------- prep1: Wp,Wn,Dp,Dn (fp32, for prep2) + bias,c128,d128p/n + Gd ----
__global__ void prep1_kernel(const float* __restrict__ theta,
                             const float* __restrict__ nw,
                             const float* __restrict__ npos,
                             const float* __restrict__ npow,
                             const float* __restrict__ colscale,
                             float* __restrict__ Wp, float* __restrict__ Wn,
                             float* __restrict__ Dp, float* __restrict__ Dn,
                             float* __restrict__ bias, float* __restrict__ c128,
                             float* __restrict__ d128p, float* __restrict__ d128n,
                             float* __restrict__ GdA) {
    int v = blockIdx.x;    // 8
    int n = threadIdx.x;   // 128
    const float inv1 = inv_f(1.0f);

    float G = 0.f;
    for (int m = 0; m < M_N; ++m) {
        float tt = thr_f(theta[m * N_N + n]);
        G += fabsf(tt * nw[(v * M_N + m) * N_N + n]);
    }
    float Gd = G + 1e-10f;
    GdA[v * 128 + n] = Gd;
    float sc = colscale[n];

    for (int m = 0; m < M_N; ++m) {
        float th = theta[m * N_N + n];
        float tt = thr_f(th);
        int ni = (v * M_N + m) * N_N + n;
        float w   = fabsf(tt * nw[ni]) / Gd;
        float pos = (tt * npos[ni] >= 0.f) ? 1.f : 0.f;
        float wp = pos * w, wn = w - wp;
        float g  = fabsf(th) * sc;
        float pm = (tt * npow[ni] >= 0.f) ? 1.f : 0.f;
        float dp = pm * g, dn = g - dp;
        if (m < 128) {
            int oi = (v * 128 + m) * 128 + n;
            Wp[oi] = wp; Wn[oi] = wn; Dp[oi] = dp; Dn[oi] = dn;
        } else if (m == 128) {
            bias[v * 128 + n]  = wp + inv1 * wn;
            c128[v * 128 + n]  = dp + inv1 * dn;
            d128p[v * 128 + n] = dp;
            d128n[v * 128 + n] = dn;
        }
    }
}

// ---------- prep2: row sums of Dp/Dn over n ----------
__global__ void prep2_kernel(const float* __restrict__ Dp, const float* __restrict__ Dn,
                             float* __restrict__ rowDp, float* __restrict__ rowDn) {
    int t = threadIdx.x;   // 1024 = (v, m<128)
    const float* dp = Dp + (size_t)t * 128;
    const float* dn = Dn + (size_t)t * 128;
    float sp = 0.f, sn = 0.f;
    for (int n4 = 0; n4 < 32; ++n4) {
        float4 a = *(const float4*)(dp + n4 * 4);
        float4 b = *(const float4*)(dn + n4 * 4);
        sp += a.x + a.y + a.z + a.w;
        sn += b.x + b.y + b.z + b.w;
    }
    rowDp[t] = sp; rowDn[t] = sn;
}

// ---------- prep_pack: fragment-linear bf16 hi/lo weight pack ----------
// Bpack[v][ks][nt][arr 0..3 = zh,zl,uh,ul][lane 0..63][j 0..7]
// lane l of frag (ks,nt): B[k = ks*32 + (l>>4)*8 + j][n = nt*16 + (l&15)]
__global__ void prep_pack_kernel(const float* __restrict__ theta,
                                 const float* __restrict__ nw,
                                 const float* __restrict__ npos,
                                 const float* __restrict__ npow,
                                 const float* __restrict__ colscale,
                                 const float* __restrict__ GdA,
                                 ushort* __restrict__ Bpack) {
    const int v = blockIdx.x >> 3, ks = blockIdx.x & 7;   // 64 blocks
    const int tid = threadIdx.x;                           // 512
    const int nt = tid >> 6, l = tid & 63;
    const int n = nt * 16 + (l & 15);
    const int k0 = ks * 32 + ((l >> 4) & 3) * 8;
    const bool lo = (ks < 4);        // k<128 -> x-side (Wp/Dp rows), else Wn/Dn
    const float Gd = GdA[v * 128 + n];
    const float sc = colscale[n];
    s16x8 zh8, zl8, uh8, ul8;
    #pragma unroll
    for (int j = 0; j < 8; ++j) {
        const int m = (k0 + j) & 127;
        float th = theta[m * N_N + n];
        float tt = thr_f(th);
        int ni = (v * M_N + m) * N_N + n;
        float wv = fabsf(tt * nw[ni]) / Gd;
        float pos = (tt * npos[ni] >= 0.f) ? 1.f : 0.f;
        float wsel = lo ? pos * wv : wv - pos * wv;
        float g = fabsf(th) * sc;
        float pm = (tt * npow[ni] >= 0.f) ? 1.f : 0.f;
        float dsel = lo ? pm * g : g - pm * g;
        ushort h16, l16;
        split2(wsel, h16, l16); zh8[j] = (short)h16; zl8[j] = (short)l16;
        split2(dsel, h16, l16); uh8[j] = (short)h16; ul8[j] = (short)l16;
    }
    size_t fb = ((((size_t)v * 8 + ks) * 8 + nt) * 4) * 512 + (size_t)l * 8;
    *(s16x8*)(Bpack + fb)        = zh8;
    *(s16x8*)(Bpack + fb + 512)  = zl8;
    *(s16x8*)(Bpack + fb + 1024) = uh8;
    *(s16x8*)(Bpack + fb + 1536) = ul8;
}

// ---------- main: MFMA dual GEMM (bf16x3 split) + activation + power ----------
__global__ __launch_bounds__(512, 4)
void pmain_kernel(const float* __restrict__ a,
                  const ushort* __restrict__ Bpack,
                  const float* __restrict__ bias, const float* __restrict__ c128,
                  const float* __restrict__ gsum,
                  const float* __restrict__ rowDp, const float* __restrict__ rowDn,
                  float* __restrict__ out, double* __restrict__ blockP) {
    __shared__ ushort As[2][BE * LDA];   // [hi|lo] A-tile: 64 rows x 256 k (x|xn)

    const int tid = threadIdx.x;
    const int v = blockIdx.y;
    const int e0 = blockIdx.x * BE;

    // ---- stage A: load x, compute xn=inv(x), hi/lo split, fold sxx ----
    float sxx = 0.f;
    {
        const int e = tid >> 3, ob = tid & 7;
        const float* arow = a + ((size_t)v * E_N + e0 + e) * N_N;
        #pragma unroll
        for (int h = 0; h < 2; ++h) {
            const int oct = ob + 8 * h;            // k-octet 0..15
            float4 xa = *(const float4*)(arow + oct * 8);
            float4 xb = *(const float4*)(arow + oct * 8 + 4);
            float4 ra = *(const float4*)(rowDp + v * 128 + oct * 8);
            float4 rb = *(const float4*)(rowDp + v * 128 + oct * 8 + 4);
            float4 sa = *(const float4*)(rowDn + v * 128 + oct * 8);
            float4 sb = *(const float4*)(rowDn + v * 128 + oct * 8 + 4);
            float xv[8] = {xa.x,xa.y,xa.z,xa.w,xb.x,xb.y,xb.z,xb.w};
            float rp[8] = {ra.x,ra.y,ra.z,ra.w,rb.x,rb.y,rb.z,rb.w};
            float rn[8] = {sa.x,sa.y,sa.z,sa.w,sb.x,sb.y,sb.z,sb.w};
            s16x8 xh8, xl8, xnh8, xnl8;
            #pragma unroll
            for (int j = 0; j < 8; ++j) {
                float x = xv[j];
                float xn = inv_f(x);
                sxx += x * x * rp[j] + xn * xn * rn[j];
                ushort h16, l16;
                split2(x, h16, l16);  xh8[j] = (short)h16;  xl8[j] = (short)l16;
                split2(xn, h16, l16); xnh8[j] = (short)h16; xnl8[j] = (short)l16;
            }
            const int base = e * LDA + oct * 8;
            *(s16x8*)&As[0][base]       = xh8;
            *(s16x8*)&As[1][base]       = xl8;
            *(s16x8*)&As[0][base + 128] = xnh8;   // xn occupies k = 128..255
            *(s16x8*)&As[1][base + 128] = xnl8;
        }
    }
    __syncthreads();

    // ---- K-loop: 8 ksteps x (4 e-tiles x 1 n-tile per wave) x 6 MFMA ----
    const int l = tid & 63, w = tid >> 6;
    const int lrow = l & 15, lk = l >> 4;
    f32x4 accz[4], accu[4];
    #pragma unroll
    for (int et = 0; et < 4; ++et) {
        accz[et] = (f32x4){0.f, 0.f, 0.f, 0.f};
        accu[et] = (f32x4){0.f, 0.f, 0.f, 0.f};
    }
    const ushort* Bbase = Bpack + (((size_t)v * 8) * 8 + w) * 4 * 512 + (size_t)l * 8;
    const int aoff0 = lrow * LDA + lk * 8;

    for (int ks = 0; ks < 8; ++ks) {
        const ushort* bp = Bbase + (size_t)ks * 16384;   // + ks*(8nt*4arr*512)
        s16x8 bzh = *(const s16x8*)(bp);
        s16x8 bzl = *(const s16x8*)(bp + 512);
        s16x8 buh = *(const s16x8*)(bp + 1024);
        s16x8 bul = *(const s16x8*)(bp + 1536);
        #pragma unroll
        for (int et = 0; et < 4; ++et) {
            const int ao = aoff0 + et * (16 * LDA) + ks * 32;
            s16x8 ah = *(const s16x8*)&As[0][ao];
            s16x8 al = *(const s16x8*)&As[1][ao];
            accz[et] = __builtin_amdgcn_mfma_f32_16x16x32_bf16(ah, bzh, accz[et], 0, 0, 0);
            accz[et] = __builtin_amdgcn_mfma_f32_16x16x32_bf16(al, bzh, accz[et], 0, 0, 0);
            accz[et] = __builtin_amdgcn_mfma_f32_16x16x32_bf16(ah, bzl, accz[et], 0, 0, 0);
            accu[et] = __builtin_amdgcn_mfma_f32_16x16x32_bf16(ah, buh, accu[et], 0, 0, 0);
            accu[et] = __builtin_amdgcn_mfma_f32_16x16x32_bf16(al, buh, accu[et], 0, 0, 0);
            accu[et] = __builtin_amdgcn_mfma_f32_16x16x32_bf16(ah, bul, accu[et], 0, 0, 0);
        }
    }

    // ---- epilogue: bias, power partials, act, LDS-transposed float4 stores ----
    const int n = w * 16 + lrow;
    const float bias_n = bias[v * 128 + n];
    const float g_n = gsum[n];
    const float c_n = c128[v * 128 + n];
    float szu = 0.f, sy2 = 0.f, ssz = 0.f;
    float* LDSf = (float*)&As[0][0];    // 16x132 f32 = 8448 B, fits As region
    __syncthreads();                     // all A reads done before reuse
    #pragma unroll
    for (int et = 0; et < 4; ++et) {
        #pragma unroll
        for (int r = 0; r < 4; ++r) {
            float z = accz[et][r] + bias_n;   // C/D: col=lane&15, row=(lane>>4)*4+r
            float u = accu[et][r];
            szu += z * u;
            sy2 += z * z * g_n;
            ssz += z * c_n;
            LDSf[(lk * 4 + r) * LDF + n] = act_f(z);
        }
        __syncthreads();
        {
            const int row = tid >> 5, c4 = tid & 31;
            float4 o4 = *(float4*)&LDSf[row * LDF + c4 * 4];
            *(float4*)(out + ((size_t)v * E_N + e0 + et * 16 + row) * N_N + c4 * 4) = o4;
        }
        __syncthreads();
    }

    float P = sxx - 2.0f * (szu + ssz) + sy2;
    #pragma unroll
    for (int off = 32; off > 0; off >>= 1) P += __shfl_down(P, off, 64);
    if (l == 0) LDSf[w] = P;
    __syncthreads();
    if (tid == 0) {
        double tot = 0.0;
        #pragma unroll
        for (int i = 0; i < 8; ++i) tot += (double)LDSf[i];
        blockP[blockIdx.y * gridDim.x + blockIdx.x] = tot;
    }
}

// ---------- finalize ----------
__global__ void pfinal_kernel(const double* __restrict__ blockP,
                              const float* __restrict__ d128p,
                              const float* __restrict__ d128n,
                              float* __restrict__ outP) {
    __shared__ double sd[256];
    int t = threadIdx.x;
    double s = 0.0;
    for (int i = t; i < 4096; i += 256) s += blockP[i];
    float inv1 = inv_f(1.0f);
    double i1sq = (double)inv1 * (double)inv1;
    double cc = 0.0;
    for (int i = t; i < V_N * 128; i += 256)
        cc += (double)d128p[i] + i1sq * (double)d128n[i];
    s += cc * (double)E_N;
    sd[t] = s;
    __syncthreads();
    for (int off = 128; off > 0; off >>= 1) {
        if (t < off) sd[t] += sd[t + off];
        __syncthreads();
    }
    if (t == 0) outP[0] = (float)(sd[0] / ((double)E_N * (double)V_N));
}

extern "C" void kernel_launch(void* const* d_in, const int* in_sizes, int n_in,
                              void* d_out, int out_size, void* d_ws, size_t ws_size,
                              hipStream_t stream) {
    const float* a     = (const float*)d_in[0];
    const float* theta = (const float*)d_in[1];
    const float* nw    = (const float*)d_in[2];
    const float* npos  = (const float*)d_in[3];
    const float* npow  = (const float*)d_in[4];
    float* out = (float*)d_out;

    // workspace: blockP doubles, fp32 arrays, then Bpack (bf16) ~2.7 MB total
    double* blockP = (double*)d_ws;                       // 4096 doubles
    float* fb = (float*)((char*)d_ws + 4096 * sizeof(double));
    float* Wp = fb;                   // 8*128*128
    float* Wn = Wp + 131072;
    float* Dp = Wn + 131072;
    float* Dn = Dp + 131072;
    float* biasA = Dn + 131072;       // 1024
    float* c128A = biasA + 1024;      // 1024
    float* gsumA = c128A + 1024;      // 128
    float* colsc = gsumA + 128;       // 128
    float* d128p = colsc + 128;       // 1024
    float* d128n = d128p + 1024;      // 1024
    float* rowDpA = d128n + 1024;     // 1024
    float* rowDnA = rowDpA + 1024;    // 1024
    float* GdA = rowDnA + 1024;       // 1024
    ushort* Bpack = (ushort*)(GdA + 1024);   // 8*8*8*4*512 = 1,048,576 ushorts

    prep0_kernel<<<1, 128, 0, stream>>>(theta, colsc, gsumA);
    prep1_kernel<<<8, 128, 0, stream>>>(theta, nw, npos, npow, colsc,
                                        Wp, Wn, Dp, Dn, biasA, c128A, d128p, d128n, GdA);
    prep2_kernel<<<1, 1024, 0, stream>>>(Dp, Dn, rowDpA, rowDnA);
    prep_pack_kernel<<<64, 512, 0, stream>>>(theta, nw, npos, npow, colsc, GdA, Bpack);
    dim3 grid(E_N / BE, V_N);
    pmain_kernel<<<grid, 512, 0, stream>>>(a, Bpack, biasA, c128A, gsumA,
                                           rowDpA, rowDnA, out, blockP);
    pfinal_kernel<<<1, 256, 0, stream>>>(blockP, d128p, d128n,
                                         out + (size_t)V_N * E_N * N_N);
}

// Round 10
// 313.818 us; speedup vs baseline: 3.0964x; 1.5593x over previous
//
#include <hip/hip_runtime.h>
#include <math.h>

// pLayer forward + power, MI355X. MFMA bf16 hi/lo 3-pass split GEMM.
// z[v,e,n] = sum_{k<256} A[e,k]*Bz[k,n] + bias ; A = [x | xn], Bz = [Wp;Wn]
// u[v,e,n] = A·Bu, Bu = [Dp;Dn]
// power*E*V = sxx - 2*(sum z*u + c128·Sz) + gsum·Sy2 + E*(d128p + inv1^2*d128n)
// bf16x3 split: A*B ~= Ah*Bh + Ah*Bl + Al*Bh (error ~2^-18 rel, fp32-equivalent)
// R10: prep chain parallelized (was ~317us of serial latency-bound loops);
//      tanhf -> exp-based fast tanh (rel err ~2e-7); plain div not amdgcn_rcpf.

#define V_N 8
#define E_N 32768
#define M_N 130
#define N_N 128
#define BE  64
#define LDA 264   // A-tile row stride in bf16 units (33 granules -> conflict-free)
#define LDF 132   // epilogue f32 transpose stride

typedef float f32x4 __attribute__((ext_vector_type(4)));
typedef short s16x8 __attribute__((ext_vector_type(8)));

// fp32 tanh(2.0) = 0.96402758f ; INV1 = -0.05 - 0.95*tanh(2)
#define INV1_C (-0.05f - 0.95f * 0.96402758f)

__device__ __forceinline__ float tanh_fast(float y) {
    float e = __expf(2.0f * y);          // v_exp_f32 path
    return 1.0f - 2.0f / (e + 1.0f);     // div -> v_rcp + NR refine
}
__device__ __forceinline__ float inv_f(float a) {
    return -0.05f - 0.95f * tanh_fast(2.0f * a);    // ETA_INV
}
__device__ __forceinline__ float act_f(float z) {
    return 0.01f + 0.5f * tanh_fast((z - 0.05f) * 10.0f);   // ETA
}
__device__ __forceinline__ float thr_f(float th) {
    float tc = fminf(fmaxf(th, -1.0f), 1.0f);
    return (fabsf(tc) < 0.01f) ? 0.0f : tc;
}
__device__ __forceinline__ ushort bf16_rne(float f) {
    unsigned u = __float_as_uint(f);
    return (ushort)((u + 0x7fffu + ((u >> 16) & 1u)) >> 16);
}
__device__ __forceinline__ void split2(float f, ushort& h, ushort& l) {
    ushort hh = bf16_rne(f);
    float fh = __uint_as_float(((unsigned)hh) << 16);
    h = hh;
    l = bf16_rne(f - fh);
}

// ---------- prep0: colscale[n] = PGMIN/min_m|theta|, gsum[n] = sum_m g ------
// 128 blocks (one per n) x 64 threads m-parallel, wave reduce.
__global__ void prep0_kernel(const float* __restrict__ theta,
                             float* __restrict__ colscale,
                             float* __restrict__ gsum) {
    const int n = blockIdx.x, t = threadIdx.x;
    float mn = 3.4e38f, s = 0.f;
    for (int m = t; m < M_N; m += 64) {
        float a = fabsf(theta[m * N_N + n]);
        mn = fminf(mn, a); s += a;
    }
    #pragma unroll
    for (int off = 32; off > 0; off >>= 1) {
        mn = fminf(mn, __shfl_xor(mn, off, 64));
        s += __shfl_xor(s, off, 64);
    }
    if (t == 0) {
        float sc = 0.01f / mn;
        colscale[n] = sc;
        gsum[n] = s * sc;
    }
}

// ---------- prepA: Gd[v,n] reduction + bias/c128/d128p/d128n (m=128 row) ----
// grid (128 n, 8 v) x 64 threads.
__global__ void prepA_kernel(const float* __restrict__ theta,
                             const float* __restrict__ nw,
                             const float* __restrict__ npos,
                             const float* __restrict__ npow,
                             const float* __restrict__ colscale,
                             float* __restrict__ GdA,
                             float* __restrict__ bias, float* __restrict__ c128,
                             float* __restrict__ d128p, float* __restrict__ d128n) {
    const int n = blockIdx.x, v = blockIdx.y, t = threadIdx.x;
    float G = 0.f;
    for (int m = t; m < M_N; m += 64) {
        float tt = thr_f(theta[m * N_N + n]);
        G += fabsf(tt * nw[(v * M_N + m) * N_N + n]);
    }
    #pragma unroll
    for (int off = 32; off > 0; off >>= 1) G += __shfl_xor(G, off, 64);
    if (t == 0) {
        float Gd = G + 1e-10f;
        GdA[v * 128 + n] = Gd;
        // m = 128 (const-1 column)
        float th = theta[128 * N_N + n];
        float tt = thr_f(th);
        int ni = (v * M_N + 128) * N_N + n;
        float w = fabsf(tt * nw[ni]) / Gd;
        float pos = (tt * npos[ni] >= 0.f) ? 1.f : 0.f;
        float wp = pos * w, wn = w - wp;
        float g = fabsf(th) * colscale[n];
        float pm = (tt * npow[ni] >= 0.f) ? 1.f : 0.f;
        float dp = pm * g, dn = g - dp;
        bias[v * 128 + n]  = wp + INV1_C * wn;
        c128[v * 128 + n]  = dp + INV1_C * dn;
        d128p[v * 128 + n] = dp;
        d128n[v * 128 + n] = dn;
    }
}

// ---------- prepR: rowDp[v,m] = sum_n pm*g, rowDn = sum_n (1-pm)*g ----------
// grid (128 m, 8 v) x 64 threads (2 n each), coalesced.
__global__ void prepR_kernel(const float* __restrict__ theta,
                             const float* __restrict__ npow,
                             const float* __restrict__ colscale,
                             float* __restrict__ rowDp, float* __restrict__ rowDn) {
    const int m = blockIdx.x, v = blockIdx.y, t = threadIdx.x;
    float sp = 0.f, sn = 0.f;
    for (int n = t; n < N_N; n += 64) {
        float th = theta[m * N_N + n];
        float tt = thr_f(th);
        float g = fabsf(th) * colscale[n];
        float pm = (tt * npow[(v * M_N + m) * N_N + n] >= 0.f) ? 1.f : 0.f;
        float dp = pm * g;
        sp += dp; sn += g - dp;
    }
    #pragma unroll
    for (int off = 32; off > 0; off >>= 1) {
        sp += __shfl_xor(sp, off, 64);
        sn += __shfl_xor(sn, off, 64);
    }
    if (t == 0) { rowDp[v * 128 + m] = sp; rowDn[v * 128 + m] = sn; }
}

// ---------- prep_pack: fragment-linear bf16 hi/lo weight pack ----------
// Bpack[v][ks][nt][arr 0..3 = zh,zl,uh,ul][lane 0..63][j 0..7]
// lane l of frag (ks,nt): B[k = ks*32 + (l>>4)*8 + j][n = nt*16 + (l&15)]
__global__ void prep_pack_kernel(const float* __restrict__ theta,
                                 const float* __restrict__ nw,
                                 const float* __restrict__ npos,
                                 const float* __restrict__ npow,
                                 const float* __restrict__ colscale,
                                 const float* __restrict__ GdA,
                                 ushort* __restrict__ Bpack) {
    const int v = blockIdx.x >> 3, ks = blockIdx.x & 7;   // 64 blocks
    const int tid = threadIdx.x;                           // 512
    const int nt = tid >> 6, l = tid & 63;
    const int n = nt * 16 + (l & 15);
    const int k0 = ks * 32 + ((l >> 4) & 3) * 8;
    const bool lo = (ks < 4);        // k<128 -> x-side (Wp/Dp rows), else Wn/Dn
    const float Gd = GdA[v * 128 + n];
    const float sc = colscale[n];
    s16x8 zh8, zl8, uh8, ul8;
    #pragma unroll
    for (int j = 0; j < 8; ++j) {
        const int m = (k0 + j) & 127;
        float th = theta[m * N_N + n];
        float tt = thr_f(th);
        int ni = (v * M_N + m) * N_N + n;
        float wv = fabsf(tt * nw[ni]) / Gd;
        float pos = (tt * npos[ni] >= 0.f) ? 1.f : 0.f;
        float wsel = lo ? pos * wv : wv - pos * wv;
        float g = fabsf(th) * sc;
        float pm = (tt * npow[ni] >= 0.f) ? 1.f : 0.f;
        float dsel = lo ? pm * g : g - pm * g;
        ushort h16, l16;
        split2(wsel, h16, l16); zh8[j] = (short)h16; zl8[j] = (short)l16;
        split2(dsel, h16, l16); uh8[j] = (short)h16; ul8[j] = (short)l16;
    }
    size_t fb = ((((size_t)v * 8 + ks) * 8 + nt) * 4) * 512 + (size_t)l * 8;
    *(s16x8*)(Bpack + fb)        = zh8;
    *(s16x8*)(Bpack + fb + 512)  = zl8;
    *(s16x8*)(Bpack + fb + 1024) = uh8;
    *(s16x8*)(Bpack + fb + 1536) = ul8;
}

// ---------- main: MFMA dual GEMM (bf16x3 split) + activation + power ----------
__global__ __launch_bounds__(512, 4)
void pmain_kernel(const float* __restrict__ a,
                  const ushort* __restrict__ Bpack,
                  const float* __restrict__ bias, const float* __restrict__ c128,
                  const float* __restrict__ gsum,
                  const float* __restrict__ rowDp, const float* __restrict__ rowDn,
                  float* __restrict__ out, double* __restrict__ blockP) {
    __shared__ ushort As[2][BE * LDA];   // [hi|lo] A-tile: 64 rows x 256 k (x|xn)

    const int tid = threadIdx.x;
    const int v = blockIdx.y;
    const int e0 = blockIdx.x * BE;

    // ---- stage A: load x, compute xn=inv(x), hi/lo split, fold sxx ----
    float sxx = 0.f;
    {
        const int e = tid >> 3, ob = tid & 7;
        const float* arow = a + ((size_t)v * E_N + e0 + e) * N_N;
        #pragma unroll
        for (int h = 0; h < 2; ++h) {
            const int oct = ob + 8 * h;            // k-octet 0..15
            float4 xa = *(const float4*)(arow + oct * 8);
            float4 xb = *(const float4*)(arow + oct * 8 + 4);
            float4 ra = *(const float4*)(rowDp + v * 128 + oct * 8);
            float4 rb = *(const float4*)(rowDp + v * 128 + oct * 8 + 4);
            float4 sa = *(const float4*)(rowDn + v * 128 + oct * 8);
            float4 sb = *(const float4*)(rowDn + v * 128 + oct * 8 + 4);
            float xv[8] = {xa.x,xa.y,xa.z,xa.w,xb.x,xb.y,xb.z,xb.w};
            float rp[8] = {ra.x,ra.y,ra.z,ra.w,rb.x,rb.y,rb.z,rb.w};
            float rn[8] = {sa.x,sa.y,sa.z,sa.w,sb.x,sb.y,sb.z,sb.w};
            s16x8 xh8, xl8, xnh8, xnl8;
            #pragma unroll
            for (int j = 0; j < 8; ++j) {
                float x = xv[j];
                float xn = inv_f(x);
                sxx += x * x * rp[j] + xn * xn * rn[j];
                ushort h16, l16;
                split2(x, h16, l16);  xh8[j] = (short)h16;  xl8[j] = (short)l16;
                split2(xn, h16, l16); xnh8[j] = (short)h16; xnl8[j] = (short)l16;
            }
            const int base = e * LDA + oct * 8;
            *(s16x8*)&As[0][base]       = xh8;
            *(s16x8*)&As[1][base]       = xl8;
            *(s16x8*)&As[0][base + 128] = xnh8;   // xn occupies k = 128..255
            *(s16x8*)&As[1][base + 128] = xnl8;
        }
    }
    __syncthreads();

    // ---- K-loop: 8 ksteps x (4 e-tiles x 1 n-tile per wave) x 6 MFMA ----
    const int l = tid & 63, w = tid >> 6;
    const int lrow = l & 15, lk = l >> 4;
    f32x4 accz[4], accu[4];
    #pragma unroll
    for (int et = 0; et < 4; ++et) {
        accz[et] = (f32x4){0.f, 0.f, 0.f, 0.f};
        accu[et] = (f32x4){0.f, 0.f, 0.f, 0.f};
    }
    const ushort* Bbase = Bpack + (((size_t)v * 8) * 8 + w) * 4 * 512 + (size_t)l * 8;
    const int aoff0 = lrow * LDA + lk * 8;

    for (int ks = 0; ks < 8; ++ks) {
        const ushort* bp = Bbase + (size_t)ks * 16384;   // + ks*(8nt*4arr*512)
        s16x8 bzh = *(const s16x8*)(bp);
        s16x8 bzl = *(const s16x8*)(bp + 512);
        s16x8 buh = *(const s16x8*)(bp + 1024);
        s16x8 bul = *(const s16x8*)(bp + 1536);
        #pragma unroll
        for (int et = 0; et < 4; ++et) {
            const int ao = aoff0 + et * (16 * LDA) + ks * 32;
            s16x8 ah = *(const s16x8*)&As[0][ao];
            s16x8 al = *(const s16x8*)&As[1][ao];
            accz[et] = __builtin_amdgcn_mfma_f32_16x16x32_bf16(ah, bzh, accz[et], 0, 0, 0);
            accz[et] = __builtin_amdgcn_mfma_f32_16x16x32_bf16(al, bzh, accz[et], 0, 0, 0);
            accz[et] = __builtin_amdgcn_mfma_f32_16x16x32_bf16(ah, bzl, accz[et], 0, 0, 0);
            accu[et] = __builtin_amdgcn_mfma_f32_16x16x32_bf16(ah, buh, accu[et], 0, 0, 0);
            accu[et] = __builtin_amdgcn_mfma_f32_16x16x32_bf16(al, buh, accu[et], 0, 0, 0);
            accu[et] = __builtin_amdgcn_mfma_f32_16x16x32_bf16(ah, bul, accu[et], 0, 0, 0);
        }
    }

    // ---- epilogue: bias, power partials, act, LDS-transposed float4 stores ----
    const int n = w * 16 + lrow;
    const float bias_n = bias[v * 128 + n];
    const float g_n = gsum[n];
    const float c_n = c128[v * 128 + n];
    float szu = 0.f, sy2 = 0.f, ssz = 0.f;
    float* LDSf = (float*)&As[0][0];    // 16x132 f32 = 8448 B, fits As region
    __syncthreads();                     // all A reads done before reuse
    #pragma unroll
    for (int et = 0; et < 4; ++et) {
        #pragma unroll
        for (int r = 0; r < 4; ++r) {
            float z = accz[et][r] + bias_n;   // C/D: col=lane&15, row=(lane>>4)*4+r
            float u = accu[et][r];
            szu += z * u;
            sy2 += z * z * g_n;
            ssz += z * c_n;
            LDSf[(lk * 4 + r) * LDF + n] = act_f(z);
        }
        __syncthreads();
        {
            const int row = tid >> 5, c4 = tid & 31;
            float4 o4 = *(float4*)&LDSf[row * LDF + c4 * 4];
            *(float4*)(out + ((size_t)v * E_N + e0 + et * 16 + row) * N_N + c4 * 4) = o4;
        }
        __syncthreads();
    }

    float P = sxx - 2.0f * (szu + ssz) + sy2;
    #pragma unroll
    for (int off = 32; off > 0; off >>= 1) P += __shfl_down(P, off, 64);
    if (l == 0) LDSf[w] = P;
    __syncthreads();
    if (tid == 0) {
        double tot = 0.0;
        #pragma unroll
        for (int i = 0; i < 8; ++i) tot += (double)LDSf[i];
        blockP[blockIdx.y * gridDim.x + blockIdx.x] = tot;
    }
}

// ---------- finalize ----------
__global__ void pfinal_kernel(const double* __restrict__ blockP,
                              const float* __restrict__ d128p,
                              const float* __restrict__ d128n,
                              float* __restrict__ outP) {
    __shared__ double sd[256];
    int t = threadIdx.x;
    double s = 0.0;
    for (int i = t; i < 4096; i += 256) s += blockP[i];
    double i1sq = (double)INV1_C * (double)INV1_C;
    double cc = 0.0;
    for (int i = t; i < V_N * 128; i += 256)
        cc += (double)d128p[i] + i1sq * (double)d128n[i];
    s += cc * (double)E_N;      // Sx2[v,128]=E, Sxn2[v,128]=E*inv1^2
    sd[t] = s;
    __syncthreads();
    for (int off = 128; off > 0; off >>= 1) {
        if (t < off) sd[t] += sd[t + off];
        __syncthreads();
    }
    if (t == 0) outP[0] = (float)(sd[0] / ((double)E_N * (double)V_N));
}

extern "C" void kernel_launch(void* const* d_in, const int* in_sizes, int n_in,
                              void* d_out, int out_size, void* d_ws, size_t ws_size,
                              hipStream_t stream) {
    const float* a     = (const float*)d_in[0];
    const float* theta = (const float*)d_in[1];
    const float* nw    = (const float*)d_in[2];
    const float* npos  = (const float*)d_in[3];
    const float* npow  = (const float*)d_in[4];
    float* out = (float*)d_out;

    // workspace: blockP doubles, small fp32 arrays, then Bpack (bf16) ~2.2 MB
    double* blockP = (double*)d_ws;                       // 4096 doubles
    float* fb = (float*)((char*)d_ws + 4096 * sizeof(double));
    float* colsc  = fb;               // 128
    float* gsumA  = colsc + 128;      // 128
    float* GdA    = gsumA + 128;      // 1024
    float* biasA  = GdA + 1024;       // 1024
    float* c128A  = biasA + 1024;     // 1024
    float* d128p  = c128A + 1024;     // 1024
    float* d128n  = d128p + 1024;     // 1024
    float* rowDpA = d128n + 1024;     // 1024
    float* rowDnA = rowDpA + 1024;    // 1024
    ushort* Bpack = (ushort*)(rowDnA + 1024);   // 1,048,576 ushorts (16B-aligned)

    prep0_kernel<<<128, 64, 0, stream>>>(theta, colsc, gsumA);
    prepA_kernel<<<dim3(128, 8), 64, 0, stream>>>(theta, nw, npos, npow, colsc,
                                                  GdA, biasA, c128A, d128p, d128n);
    prepR_kernel<<<dim3(128, 8), 64, 0, stream>>>(theta, npow, colsc, rowDpA, rowDnA);
    prep_pack_kernel<<<64, 512, 0, stream>>>(theta, nw, npos, npow, colsc, GdA, Bpack);
    dim3 grid(E_N / BE, V_N);
    pmain_kernel<<<grid, 512, 0, stream>>>(a, Bpack, biasA, c128A, gsumA,
                                           rowDpA, rowDnA, out, blockP);
    pfinal_kernel<<<1, 256, 0, stream>>>(blockP, d128p, d128n,
                                         out + (size_t)V_N * E_N * N_N);
}